// Round 4
// baseline (481.979 us; speedup 1.0000x reference)
//
#include <hip/hip_runtime.h>

#define DIM 1024
#define NHEADS 16
#define HD 64
#define NSEQ 2048
#define MROWS 4096          // B*N
#define QKV_LD 3072

typedef __attribute__((ext_vector_type(8))) short short8;
typedef __attribute__((ext_vector_type(4))) short short4v;
typedef __attribute__((ext_vector_type(4))) float f32x4;

typedef __attribute__((address_space(1))) void gvoid_t;
typedef __attribute__((address_space(3))) void lvoid_t;

#if __has_builtin(__builtin_amdgcn_exp2f)
#define EXP2(x) __builtin_amdgcn_exp2f(x)
#else
#define EXP2(x) exp2f(x)
#endif

// K=16 bf16 MFMA: builtin name varies across ROCm versions; asm fallback.
#if __has_builtin(__builtin_amdgcn_mfma_f32_16x16x16_bf16)
#define MFMA16(a, b, c) __builtin_amdgcn_mfma_f32_16x16x16_bf16(a, b, c, 0, 0, 0)
#elif __has_builtin(__builtin_amdgcn_mfma_f32_16x16x16bf16_1k)
#define MFMA16(a, b, c) __builtin_amdgcn_mfma_f32_16x16x16bf16_1k(a, b, c, 0, 0, 0)
#else
static __device__ __forceinline__ f32x4 mfma16_asm(short4v a, short4v b, f32x4 c) {
  __asm__("v_mfma_f32_16x16x16_bf16 %0, %1, %2, %0" : "+v"(c) : "v"(a), "v"(b));
  return c;
}
#define MFMA16(a, b, c) mfma16_asm(a, b, c)
#endif

#define MFMA32(a, b, c) __builtin_amdgcn_mfma_f32_16x16x32_bf16(a, b, c, 0, 0, 0)

// exp2 arg scale: HEAD_DIM^-0.5 * log2(e)
#define EXP_SCALE 0.18033688011112042f

__device__ __forceinline__ unsigned short f2bf(float f) {
  unsigned int u = __builtin_bit_cast(unsigned int, f);
  u += 0x7FFFu + ((u >> 16) & 1u);
  return (unsigned short)(u >> 16);
}

// async global->LDS, 16B per lane; LDS dst = wave-uniform base + lane*16
__device__ __forceinline__ void gl_lds16(const void* g, void* l) {
  __builtin_amdgcn_global_load_lds((gvoid_t*)g, (lvoid_t*)l, 16, 0, 0);
}

// ---------------------------------------------------------------------------
// Kernel 1: cast x (4M), qkv_w (3M), proj_w (1M) fp32 -> bf16. 2M float4 groups.
// ---------------------------------------------------------------------------
__global__ __launch_bounds__(256) void cast_bf16_3(
    const float* __restrict__ x, const float* __restrict__ wq,
    const float* __restrict__ wp,
    unsigned short* __restrict__ xb, unsigned short* __restrict__ wqb,
    unsigned short* __restrict__ wpb)
{
  int g = blockIdx.x * 256 + threadIdx.x;   // 0 .. 2097151
  const float* src;
  unsigned short* dst;
  if (g < 1048576)            { src = x  + (size_t)g * 4;              dst = xb  + (size_t)g * 4; }
  else if (g < 1048576 + 786432) { int t = g - 1048576; src = wq + (size_t)t * 4; dst = wqb + (size_t)t * 4; }
  else                        { int t = g - 1048576 - 786432; src = wp + (size_t)t * 4; dst = wpb + (size_t)t * 4; }
  float4 v = *(const float4*)src;
  ushort4 o;
  o.x = f2bf(v.x); o.y = f2bf(v.y); o.z = f2bf(v.z); o.w = f2bf(v.w);
  *(ushort4*)dst = o;
}

// ---------------------------------------------------------------------------
// Kernel 2: NT GEMM, 128x128x32 tile. mode 1: bf16 Q/K -> oq (ld 3072),
// V -> key-tiled V^T buffer vt2[bh][n>>4][d][n&15].
// ---------------------------------------------------------------------------
__global__ __launch_bounds__(256) void gemm_nt(
    const unsigned short* __restrict__ A,
    const unsigned short* __restrict__ Bw,
    const float* __restrict__ bias,
    int K, int mode,
    unsigned short* __restrict__ oq,
    unsigned short* __restrict__ ovt,
    float* __restrict__ of)
{
  __shared__ unsigned short As[128 * 32];
  __shared__ unsigned short Bs[128 * 32];

  const int tid  = threadIdx.x;
  const int wave = tid >> 6, lane = tid & 63;
  const int quad = lane >> 4, l15 = lane & 15;
  const int mblk = blockIdx.x * 128;
  const int nblk = blockIdx.y * 128;
  const int wrow = (wave >> 1) * 64, wcol = (wave & 1) * 64;

  f32x4 acc[4][4] = {};

  const int sr = lane >> 2;                 // row within 16-row chunk
  const int sq = (lane & 3) ^ (sr & 3);     // swizzled k-chunk for this lane
  const unsigned short* aBase = A  + (size_t)(mblk + wave * 32 + sr) * K + sq * 8;
  const unsigned short* bBase = Bw + (size_t)(nblk + wave * 32 + sr) * K + sq * 8;

  for (int k0 = 0; k0 < K; k0 += 32) {
    __syncthreads();
    gl_lds16(aBase + k0,          As + (wave * 32) * 32);
    gl_lds16(aBase + 16 * K + k0, As + (wave * 32 + 16) * 32);
    gl_lds16(bBase + k0,          Bs + (wave * 32) * 32);
    gl_lds16(bBase + 16 * K + k0, Bs + (wave * 32 + 16) * 32);
    __syncthreads();

    short8 af[4], bf8[4];
#pragma unroll
    for (int mt = 0; mt < 4; ++mt) {
      int row = wrow + mt * 16 + l15;
      af[mt] = *(const short8*)(As + row * 32 + ((quad ^ (row & 3)) * 8));
    }
#pragma unroll
    for (int nt = 0; nt < 4; ++nt) {
      int row = wcol + nt * 16 + l15;
      bf8[nt] = *(const short8*)(Bs + row * 32 + ((quad ^ (row & 3)) * 8));
    }
#pragma unroll
    for (int mt = 0; mt < 4; ++mt)
#pragma unroll
      for (int nt = 0; nt < 4; ++nt)
        acc[mt][nt] = MFMA32(af[mt], bf8[nt], acc[mt][nt]);
  }

  float bv[4];
#pragma unroll
  for (int nt = 0; nt < 4; ++nt) bv[nt] = bias[nblk + wcol + nt * 16 + l15];

  if (mode == 0) {
#pragma unroll
    for (int mt = 0; mt < 4; ++mt) {
      int row0 = mblk + wrow + mt * 16 + quad * 4;
#pragma unroll
      for (int nt = 0; nt < 4; ++nt) {
        int col = nblk + wcol + nt * 16 + l15;
#pragma unroll
        for (int r = 0; r < 4; ++r)
          of[(size_t)(row0 + r) * DIM + col] = acc[mt][nt][r] + bv[nt];
      }
    }
  } else if (nblk < 2048) {
    // Q or K block -> qkv buffer, bf16
#pragma unroll
    for (int mt = 0; mt < 4; ++mt) {
      int row0 = mblk + wrow + mt * 16 + quad * 4;
#pragma unroll
      for (int nt = 0; nt < 4; ++nt) {
        int col = nblk + wcol + nt * 16 + l15;
#pragma unroll
        for (int r = 0; r < 4; ++r)
          oq[(size_t)(row0 + r) * QKV_LD + col] = f2bf(acc[mt][nt][r] + bv[nt]);
      }
    }
  } else {
    // V -> key-tiled transposed buffer: vt2[bh][n>>4][d][n&15]
#pragma unroll
    for (int mt = 0; mt < 4; ++mt) {
      int row0 = mblk + wrow + mt * 16 + quad * 4;
      int n0 = row0 & (NSEQ - 1);
      int bb = row0 >> 11;
#pragma unroll
      for (int nt = 0; nt < 4; ++nt) {
        int colr = (nblk - 2048) + wcol + nt * 16 + l15;
        int bh = bb * NHEADS + (colr >> 6);
        int d  = colr & 63;
        ushort4 pk;
        pk.x = f2bf(acc[mt][nt][0] + bv[nt]);
        pk.y = f2bf(acc[mt][nt][1] + bv[nt]);
        pk.z = f2bf(acc[mt][nt][2] + bv[nt]);
        pk.w = f2bf(acc[mt][nt][3] + bv[nt]);
        *(ushort4*)(ovt + (size_t)bh * 131072 + (n0 >> 4) * 1024 + d * 16 + (n0 & 15)) = pk;
      }
    }
  }
}

// ---------------------------------------------------------------------------
// Kernel 4: NT GEMM for proj: 64(M)x128(N)x32 tile -> 512 blocks (2/CU).
// ---------------------------------------------------------------------------
__global__ __launch_bounds__(256) void gemm_nt64(
    const unsigned short* __restrict__ A,
    const unsigned short* __restrict__ Bw,
    const float* __restrict__ bias,
    int K,
    float* __restrict__ of)
{
  __shared__ unsigned short As[64 * 32];
  __shared__ unsigned short Bs[128 * 32];

  const int tid  = threadIdx.x;
  const int wave = tid >> 6, lane = tid & 63;
  const int quad = lane >> 4, l15 = lane & 15;
  const int mblk = blockIdx.x * 64;
  const int nblk = blockIdx.y * 128;
  const int wrow = (wave >> 1) * 32, wcol = (wave & 1) * 64;

  f32x4 acc[2][4] = {};

  const int sr = lane >> 2;
  const int sq = (lane & 3) ^ (sr & 3);
  const unsigned short* aBase = A  + (size_t)(mblk + wave * 16 + sr) * K + sq * 8;
  const unsigned short* bBase = Bw + (size_t)(nblk + wave * 32 + sr) * K + sq * 8;

  for (int k0 = 0; k0 < K; k0 += 32) {
    __syncthreads();
    gl_lds16(aBase + k0,          As + (wave * 16) * 32);
    gl_lds16(bBase + k0,          Bs + (wave * 32) * 32);
    gl_lds16(bBase + 16 * K + k0, Bs + (wave * 32 + 16) * 32);
    __syncthreads();

    short8 af[2], bf8[4];
#pragma unroll
    for (int mt = 0; mt < 2; ++mt) {
      int row = wrow + mt * 16 + l15;
      af[mt] = *(const short8*)(As + row * 32 + ((quad ^ (row & 3)) * 8));
    }
#pragma unroll
    for (int nt = 0; nt < 4; ++nt) {
      int row = wcol + nt * 16 + l15;
      bf8[nt] = *(const short8*)(Bs + row * 32 + ((quad ^ (row & 3)) * 8));
    }
#pragma unroll
    for (int mt = 0; mt < 2; ++mt)
#pragma unroll
      for (int nt = 0; nt < 4; ++nt)
        acc[mt][nt] = MFMA32(af[mt], bf8[nt], acc[mt][nt]);
  }

  float bv[4];
#pragma unroll
  for (int nt = 0; nt < 4; ++nt) bv[nt] = bias[nblk + wcol + nt * 16 + l15];

#pragma unroll
  for (int mt = 0; mt < 2; ++mt) {
    int row0 = mblk + wrow + mt * 16 + quad * 4;
#pragma unroll
    for (int nt = 0; nt < 4; ++nt) {
      int col = nblk + wcol + nt * 16 + l15;
#pragma unroll
      for (int r = 0; r < 4; ++r)
        of[(size_t)(row0 + r) * DIM + col] = acc[mt][nt][r] + bv[nt];
    }
  }
}

// ---------------------------------------------------------------------------
// Kernel 3: fused attention, wave-private key-split, barrier-free K-loop.
// Block = (b,h) x 64 q. Wave w owns keys {kk + w*16}; stages its own K rows
// (16x64) and V^T slab (64x16) into private double-buffered LDS; pipeline via
// s_waitcnt vmcnt(4). S^T = K·Q^T (K=32), P^T packed in-register = B-operand
// of K=16 MFMA, O^T += V^T·P^T. Cross-wave O/lsum reduction via LDS atomics.
// ---------------------------------------------------------------------------
__global__ __launch_bounds__(256, 3) void attn_fused(
    const unsigned short* __restrict__ qkv,   // (4096, 3072) bf16; Q [0,1024), K [1024,2048)
    const unsigned short* __restrict__ vt2,   // (32, 128, 64, 16) bf16 key-tiled V^T
    unsigned short* __restrict__ aout)        // (4096, 1024) bf16
{
  __shared__ unsigned short stage[2][4][2048]; // per buf, per wave: K 16x64 | V^T 64x16
  __shared__ float accS[4096];                 // O[q][d-swizzled] fp32
  __shared__ float lsumS[64];

  const int tid  = threadIdx.x;
  const int wave = tid >> 6, lane = tid & 63;
  const int quad = lane >> 4, l15 = lane & 15;
  const int bh = blockIdx.x, b = bh >> 4, h = bh & 15;
  const int q0 = blockIdx.y * 64;
  const size_t qkvB = (size_t)b * NSEQ * QKV_LD;

  // zero accumulation buffers (must precede any wave's epilogue atomics)
  for (int i = tid; i < 4096; i += 256) accS[i] = 0.f;
  if (tid < 64) lsumS[tid] = 0.f;
  __syncthreads();

  // Q fragments: all 64 q (B-operand: n=q=l15, k=d=ks*32+quad*8+j), held in regs
  short8 qf[4][2];
#pragma unroll
  for (int qt = 0; qt < 4; ++qt)
#pragma unroll
    for (int ks = 0; ks < 2; ++ks)
      qf[qt][ks] = *(const short8*)(qkv + qkvB +
          (size_t)(q0 + qt * 16 + l15) * QKV_LD + h * HD + ks * 32 + quad * 8);

  const int sr8 = lane >> 3, sp8 = lane & 7;
  // K staging: instr j stages rows j*8+sr8 of the wave's 16 keys, chunk sp8^sr8
  const unsigned short* kStage = qkv + qkvB + DIM + h * HD
      + (size_t)(wave * 16 + sr8) * QKV_LD + (sp8 ^ sr8) * 8;
  // V staging: contiguous 2KB tile vt2[bh][kk/16 + wave][*][*]
  const unsigned short* vStage = vt2 + (size_t)bh * 131072 + wave * 1024 + lane * 8;

  unsigned short* slab0 = &stage[0][wave][0];
  unsigned short* slab1 = &stage[1][wave][0];

  f32x4 oacc[4][4] = {};   // [dt][qt]: O^T[d=dt*16+quad*4+r][q=qt*16+l15]
  float lsum[4] = {};

  auto compute = [&](const unsigned short* cur) {
    // K A-frags: m=key(rel)=l15, k=d (swizzled chunks)
    short8 kf0 = *(const short8*)(cur + l15 * 64 + ((quad       ^ (l15 & 7)) * 8));
    short8 kf1 = *(const short8*)(cur + l15 * 64 + (((4 + quad) ^ (l15 & 7)) * 8));
    f32x4 sacc[4] = {};
#pragma unroll
    for (int qt = 0; qt < 4; ++qt) {
      sacc[qt] = MFMA32(kf0, qf[qt][0], sacc[qt]);
      sacc[qt] = MFMA32(kf1, qf[qt][1], sacc[qt]);
    }
    // V^T A-frags: m=d=dt*16+l15, k=key(rel)=quad*4+j
    short4v vf[4];
#pragma unroll
    for (int dt = 0; dt < 4; ++dt)
      vf[dt] = *(const short4v*)(cur + 1024 + (dt * 16 + l15) * 16 + quad * 4);
    // softmax (no max-sub; logits bounded) + PV, all in registers
#pragma unroll
    for (int qt = 0; qt < 4; ++qt) {
      float p0 = EXP2(sacc[qt][0] * EXP_SCALE);
      float p1 = EXP2(sacc[qt][1] * EXP_SCALE);
      float p2 = EXP2(sacc[qt][2] * EXP_SCALE);
      float p3 = EXP2(sacc[qt][3] * EXP_SCALE);
      lsum[qt] += (p0 + p1) + (p2 + p3);
      unsigned r0 = __builtin_bit_cast(unsigned, p0) + 0x8000u;
      unsigned r1 = __builtin_bit_cast(unsigned, p1) + 0x8000u;
      unsigned r2 = __builtin_bit_cast(unsigned, p2) + 0x8000u;
      unsigned r3 = __builtin_bit_cast(unsigned, p3) + 0x8000u;
      uint2 pd;
      pd.x = __builtin_amdgcn_perm(r1, r0, 0x07060302u);
      pd.y = __builtin_amdgcn_perm(r3, r2, 0x07060302u);
      short4v pf = __builtin_bit_cast(short4v, pd);
#pragma unroll
      for (int dt = 0; dt < 4; ++dt)
        oacc[dt][qt] = MFMA16(vf[dt], pf, oacc[dt][qt]);
    }
  };

  // prologue: stage tile 0 into buf0
  gl_lds16(kStage,                 slab0);
  gl_lds16(kStage + 8 * QKV_LD,    slab0 + 512);
  gl_lds16(vStage,                 slab0 + 1024);
  gl_lds16(vStage + 512,           slab0 + 1536);

  const unsigned short* kNext = kStage + (size_t)64 * QKV_LD;
  const unsigned short* vNext = vStage + 4096;

#pragma unroll 2
  for (int t = 0; t < 31; ++t) {
    unsigned short* cur = (t & 1) ? slab1 : slab0;
    unsigned short* nxt = (t & 1) ? slab0 : slab1;
    gl_lds16(kNext,                nxt);
    gl_lds16(kNext + 8 * QKV_LD,   nxt + 512);
    gl_lds16(vNext,                nxt + 1024);
    gl_lds16(vNext + 512,          nxt + 1536);
    kNext += (size_t)64 * QKV_LD;
    vNext += 4096;
    __asm__ volatile("s_waitcnt vmcnt(4)" ::: "memory");
    compute(cur);
  }
  __asm__ volatile("s_waitcnt vmcnt(0)" ::: "memory");
  compute(slab1);

  // cross-wave reduction: lsum then O partials
#pragma unroll
  for (int qt = 0; qt < 4; ++qt) {
    float s = lsum[qt];
    s += __shfl_xor(s, 16);
    s += __shfl_xor(s, 32);
    if (quad == 0) atomicAdd(&lsumS[qt * 16 + l15], s);
  }
#pragma unroll
  for (int dt = 0; dt < 4; ++dt)
#pragma unroll
    for (int qt = 0; qt < 4; ++qt) {
      int q = qt * 16 + l15;
      int dbase = dt * 16 + quad * 4;
#pragma unroll
      for (int r = 0; r < 4; ++r)
        atomicAdd(&accS[q * 64 + ((dbase + r + q) & 63)], oacc[dt][qt][r]);
    }
  __syncthreads();

  // store: wave w -> q rows w*16..+15; lane = d (coalesced 128B rows)
  const int d = lane;
  for (int qq = 0; qq < 16; ++qq) {
    int q = wave * 16 + qq;
    float inv = 1.0f / lsumS[q];
    float v = accS[q * 64 + ((d + q) & 63)] * inv;
    aout[(size_t)(b * NSEQ + q0 + q) * DIM + h * HD + d] = f2bf(v);
  }
}

// ---------------------------------------------------------------------------
extern "C" void kernel_launch(void* const* d_in, const int* in_sizes, int n_in,
                              void* d_out, int out_size, void* d_ws, size_t ws_size,
                              hipStream_t stream) {
  (void)in_sizes; (void)n_in; (void)out_size; (void)ws_size;
  const float* x      = (const float*)d_in[0];
  const float* qkv_w  = (const float*)d_in[1];
  const float* qkv_b  = (const float*)d_in[2];
  const float* proj_w = (const float*)d_in[3];
  const float* proj_b = (const float*)d_in[4];
  float* out = (float*)d_out;

  char* ws = (char*)d_ws;
  unsigned short* xb   = (unsigned short*)(ws);                       // 8 MB
  unsigned short* wqb  = (unsigned short*)(ws + ( 8u << 20));         // 6 MB
  unsigned short* wpb  = (unsigned short*)(ws + (14u << 20));         // 2 MB
  unsigned short* qkv  = (unsigned short*)(ws + (16u << 20));         // 24 MB
  unsigned short* vtw  = (unsigned short*)(ws + (40u << 20));         // 8 MB
  unsigned short* attn = (unsigned short*)(ws + (48u << 20));         // 8 MB

  cast_bf16_3<<<8192, 256, 0, stream>>>(x, qkv_w, proj_w, xb, wqb, wpb);
  gemm_nt<<<dim3(32, 24), 256, 0, stream>>>(xb, wqb, qkv_b, DIM, 1, qkv, vtw, nullptr);
  attn_fused<<<dim3(32, 32), 256, 0, stream>>>(qkv, vtw, attn);
  gemm_nt64<<<dim3(64, 8), 256, 0, stream>>>(attn, wpb, proj_b, DIM, out);
}

// Round 6
// 266.261 us; speedup vs baseline: 1.8102x; 1.8102x over previous
//
#include <hip/hip_runtime.h>

#define DIM 1024
#define NHEADS 16
#define HD 64
#define NSEQ 2048
#define MROWS 4096          // B*N
#define QKV_LD 3072

typedef __attribute__((ext_vector_type(8))) short short8;
typedef __attribute__((ext_vector_type(4))) short short4v;
typedef __attribute__((ext_vector_type(4))) float f32x4;

typedef __attribute__((address_space(1))) void gvoid_t;
typedef __attribute__((address_space(3))) void lvoid_t;

#if __has_builtin(__builtin_amdgcn_exp2f)
#define EXP2(x) __builtin_amdgcn_exp2f(x)
#else
#define EXP2(x) exp2f(x)
#endif

// K=16 bf16 MFMA: builtin name varies across ROCm versions; asm fallback.
#if __has_builtin(__builtin_amdgcn_mfma_f32_16x16x16_bf16)
#define MFMA16(a, b, c) __builtin_amdgcn_mfma_f32_16x16x16_bf16(a, b, c, 0, 0, 0)
#elif __has_builtin(__builtin_amdgcn_mfma_f32_16x16x16bf16_1k)
#define MFMA16(a, b, c) __builtin_amdgcn_mfma_f32_16x16x16bf16_1k(a, b, c, 0, 0, 0)
#else
static __device__ __forceinline__ f32x4 mfma16_asm(short4v a, short4v b, f32x4 c) {
  __asm__("v_mfma_f32_16x16x16_bf16 %0, %1, %2, %0" : "+v"(c) : "v"(a), "v"(b));
  return c;
}
#define MFMA16(a, b, c) mfma16_asm(a, b, c)
#endif

#define MFMA32(a, b, c) __builtin_amdgcn_mfma_f32_16x16x32_bf16(a, b, c, 0, 0, 0)

// exp2 arg scale: HEAD_DIM^-0.5 * log2(e)  (folded into Q at GEMM epilogue)
#define EXP_SCALE 0.18033688011112042f

__device__ __forceinline__ unsigned short f2bf(float f) {
  unsigned int u = __builtin_bit_cast(unsigned int, f);
  u += 0x7FFFu + ((u >> 16) & 1u);
  return (unsigned short)(u >> 16);
}

// async global->LDS, 16B per lane; LDS dst = wave-uniform base + lane*16
__device__ __forceinline__ void gl_lds16(const void* g, void* l) {
  __builtin_amdgcn_global_load_lds((gvoid_t*)g, (lvoid_t*)l, 16, 0, 0);
}

// ---------------------------------------------------------------------------
// Kernel 1: cast x (4M), qkv_w (3M), proj_w (1M) fp32 -> bf16. 2M float4 groups.
// ---------------------------------------------------------------------------
__global__ __launch_bounds__(256) void cast_bf16_3(
    const float* __restrict__ x, const float* __restrict__ wq,
    const float* __restrict__ wp,
    unsigned short* __restrict__ xb, unsigned short* __restrict__ wqb,
    unsigned short* __restrict__ wpb)
{
  int g = blockIdx.x * 256 + threadIdx.x;   // 0 .. 2097151
  const float* src;
  unsigned short* dst;
  if (g < 1048576)            { src = x  + (size_t)g * 4;              dst = xb  + (size_t)g * 4; }
  else if (g < 1048576 + 786432) { int t = g - 1048576; src = wq + (size_t)t * 4; dst = wqb + (size_t)t * 4; }
  else                        { int t = g - 1048576 - 786432; src = wp + (size_t)t * 4; dst = wpb + (size_t)t * 4; }
  float4 v = *(const float4*)src;
  ushort4 o;
  o.x = f2bf(v.x); o.y = f2bf(v.y); o.z = f2bf(v.z); o.w = f2bf(v.w);
  *(ushort4*)dst = o;
}

// ---------------------------------------------------------------------------
// Kernel 2: NT GEMM, 128x128x32 tile. mode 1: bf16 Q/K -> oq (ld 3072),
// Q columns pre-scaled by EXP_SCALE; V -> key-tiled V^T vt2[bh][n>>4][d][n&15].
// ---------------------------------------------------------------------------
__global__ __launch_bounds__(256) void gemm_nt(
    const unsigned short* __restrict__ A,
    const unsigned short* __restrict__ Bw,
    const float* __restrict__ bias,
    int K, int mode,
    unsigned short* __restrict__ oq,
    unsigned short* __restrict__ ovt,
    float* __restrict__ of)
{
  __shared__ unsigned short As[128 * 32];
  __shared__ unsigned short Bs[128 * 32];

  const int tid  = threadIdx.x;
  const int wave = tid >> 6, lane = tid & 63;
  const int quad = lane >> 4, l15 = lane & 15;
  const int mblk = blockIdx.x * 128;
  const int nblk = blockIdx.y * 128;
  const int wrow = (wave >> 1) * 64, wcol = (wave & 1) * 64;

  f32x4 acc[4][4] = {};

  const int sr = lane >> 2;                 // row within 16-row chunk
  const int sq = (lane & 3) ^ (sr & 3);     // swizzled k-chunk for this lane
  const unsigned short* aBase = A  + (size_t)(mblk + wave * 32 + sr) * K + sq * 8;
  const unsigned short* bBase = Bw + (size_t)(nblk + wave * 32 + sr) * K + sq * 8;

  for (int k0 = 0; k0 < K; k0 += 32) {
    __syncthreads();
    gl_lds16(aBase + k0,          As + (wave * 32) * 32);
    gl_lds16(aBase + 16 * K + k0, As + (wave * 32 + 16) * 32);
    gl_lds16(bBase + k0,          Bs + (wave * 32) * 32);
    gl_lds16(bBase + 16 * K + k0, Bs + (wave * 32 + 16) * 32);
    __syncthreads();

    short8 af[4], bf8[4];
#pragma unroll
    for (int mt = 0; mt < 4; ++mt) {
      int row = wrow + mt * 16 + l15;
      af[mt] = *(const short8*)(As + row * 32 + ((quad ^ (row & 3)) * 8));
    }
#pragma unroll
    for (int nt = 0; nt < 4; ++nt) {
      int row = wcol + nt * 16 + l15;
      bf8[nt] = *(const short8*)(Bs + row * 32 + ((quad ^ (row & 3)) * 8));
    }
#pragma unroll
    for (int mt = 0; mt < 4; ++mt)
#pragma unroll
      for (int nt = 0; nt < 4; ++nt)
        acc[mt][nt] = MFMA32(af[mt], bf8[nt], acc[mt][nt]);
  }

  float bv[4];
#pragma unroll
  for (int nt = 0; nt < 4; ++nt) bv[nt] = bias[nblk + wcol + nt * 16 + l15];

  if (mode == 0) {
#pragma unroll
    for (int mt = 0; mt < 4; ++mt) {
      int row0 = mblk + wrow + mt * 16 + quad * 4;
#pragma unroll
      for (int nt = 0; nt < 4; ++nt) {
        int col = nblk + wcol + nt * 16 + l15;
#pragma unroll
        for (int r = 0; r < 4; ++r)
          of[(size_t)(row0 + r) * DIM + col] = acc[mt][nt][r] + bv[nt];
      }
    }
  } else if (nblk < 2048) {
    // Q (pre-scaled by EXP_SCALE) or K block -> qkv buffer, bf16
    const float qs = (nblk < 1024) ? EXP_SCALE : 1.0f;
#pragma unroll
    for (int mt = 0; mt < 4; ++mt) {
      int row0 = mblk + wrow + mt * 16 + quad * 4;
#pragma unroll
      for (int nt = 0; nt < 4; ++nt) {
        int col = nblk + wcol + nt * 16 + l15;
#pragma unroll
        for (int r = 0; r < 4; ++r)
          oq[(size_t)(row0 + r) * QKV_LD + col] = f2bf((acc[mt][nt][r] + bv[nt]) * qs);
      }
    }
  } else {
    // V -> key-tiled transposed buffer: vt2[bh][n>>4][d][n&15]
#pragma unroll
    for (int mt = 0; mt < 4; ++mt) {
      int row0 = mblk + wrow + mt * 16 + quad * 4;
      int n0 = row0 & (NSEQ - 1);
      int bb = row0 >> 11;
#pragma unroll
      for (int nt = 0; nt < 4; ++nt) {
        int colr = (nblk - 2048) + wcol + nt * 16 + l15;
        int bh = bb * NHEADS + (colr >> 6);
        int d  = colr & 63;
        ushort4 pk;
        pk.x = f2bf(acc[mt][nt][0] + bv[nt]);
        pk.y = f2bf(acc[mt][nt][1] + bv[nt]);
        pk.z = f2bf(acc[mt][nt][2] + bv[nt]);
        pk.w = f2bf(acc[mt][nt][3] + bv[nt]);
        *(ushort4*)(ovt + (size_t)bh * 131072 + (n0 >> 4) * 1024 + d * 16 + (n0 & 15)) = pk;
      }
    }
  }
}

// ---------------------------------------------------------------------------
// Kernel 4: NT GEMM for proj: 64(M)x128(N)x32 tile -> 512 blocks (2/CU).
// ---------------------------------------------------------------------------
__global__ __launch_bounds__(256) void gemm_nt64(
    const unsigned short* __restrict__ A,
    const unsigned short* __restrict__ Bw,
    const float* __restrict__ bias,
    int K,
    float* __restrict__ of)
{
  __shared__ unsigned short As[64 * 32];
  __shared__ unsigned short Bs[128 * 32];

  const int tid  = threadIdx.x;
  const int wave = tid >> 6, lane = tid & 63;
  const int quad = lane >> 4, l15 = lane & 15;
  const int mblk = blockIdx.x * 64;
  const int nblk = blockIdx.y * 128;
  const int wrow = (wave >> 1) * 32, wcol = (wave & 1) * 64;

  f32x4 acc[2][4] = {};

  const int sr = lane >> 2;
  const int sq = (lane & 3) ^ (sr & 3);
  const unsigned short* aBase = A  + (size_t)(mblk + wave * 16 + sr) * K + sq * 8;
  const unsigned short* bBase = Bw + (size_t)(nblk + wave * 32 + sr) * K + sq * 8;

  for (int k0 = 0; k0 < K; k0 += 32) {
    __syncthreads();
    gl_lds16(aBase + k0,          As + (wave * 16) * 32);
    gl_lds16(bBase + k0,          Bs + (wave * 32) * 32);
    gl_lds16(bBase + 16 * K + k0, Bs + (wave * 32 + 16) * 32);
    __syncthreads();

    short8 af[2], bf8[4];
#pragma unroll
    for (int mt = 0; mt < 2; ++mt) {
      int row = wrow + mt * 16 + l15;
      af[mt] = *(const short8*)(As + row * 32 + ((quad ^ (row & 3)) * 8));
    }
#pragma unroll
    for (int nt = 0; nt < 4; ++nt) {
      int row = wcol + nt * 16 + l15;
      bf8[nt] = *(const short8*)(Bs + row * 32 + ((quad ^ (row & 3)) * 8));
    }
#pragma unroll
    for (int mt = 0; mt < 2; ++mt)
#pragma unroll
      for (int nt = 0; nt < 4; ++nt)
        acc[mt][nt] = MFMA32(af[mt], bf8[nt], acc[mt][nt]);
  }

  float bv[4];
#pragma unroll
  for (int nt = 0; nt < 4; ++nt) bv[nt] = bias[nblk + wcol + nt * 16 + l15];

#pragma unroll
  for (int mt = 0; mt < 2; ++mt) {
    int row0 = mblk + wrow + mt * 16 + quad * 4;
#pragma unroll
    for (int nt = 0; nt < 4; ++nt) {
      int col = nblk + wcol + nt * 16 + l15;
#pragma unroll
      for (int r = 0; r < 4; ++r)
        of[(size_t)(row0 + r) * DIM + col] = acc[mt][nt][r] + bv[nt];
    }
  }
}

// ---------------------------------------------------------------------------
// Kernel 3: fused attention, wave-private key-split, barrier-free K-loop.
// Block = (b,h) x 64 q. Wave w owns key-tiles; stages its own K rows (16x64)
// + V^T slab (64x16) into private double-buffered LDS.
// ORDERING: before re-staging a slab we execute `s_waitcnt lgkmcnt(0)` inside
// an asm memory clobber — guarantees all ds_reads of that slab have EXECUTED
// before the DMA overwrite can issue, and stops the compiler sinking LDS
// reads past the stage (round-5 failure: stage(X) adjacent to compute(X)
// corrupted V-frags when the DMA landed before sunk ds_reads; round-4's
// spill stalls had masked the same race).
// launch_bounds(256,2): VGPR cap 256 — (256,3) caused 354MB scratch spill.
// ---------------------------------------------------------------------------
__global__ __launch_bounds__(256, 2) void attn_fused(
    const unsigned short* __restrict__ qkv,   // (4096, 3072) bf16; Q*c [0,1024), K [1024,2048)
    const unsigned short* __restrict__ vt2,   // (32, 128, 64, 16) bf16 key-tiled V^T
    unsigned short* __restrict__ aout)        // (4096, 1024) bf16
{
  __shared__ unsigned short stage[2][4][2048]; // per buf, per wave: K 16x64 | V^T 64x16
  __shared__ float accS[4096];                 // O[q][d-swizzled] fp32
  __shared__ float lsumS[64];

  const int tid  = threadIdx.x;
  const int wave = tid >> 6, lane = tid & 63;
  const int quad = lane >> 4, l15 = lane & 15;
  const int id = blockIdx.x;
  // XCD-aware decode (XCD ~ id%8): XCD k serves bh {4k..4k+3} -> K/V fits its L2
  const int bh = (id & 7) * 4 + ((id >> 3) & 3);
  const int b = bh >> 4, h = bh & 15;
  const int q0 = (id >> 5) * 64;
  const size_t qkvB = (size_t)b * NSEQ * QKV_LD;

  // zero accumulation buffers (ordered before any wave's epilogue atomics)
  for (int i = tid; i < 4096; i += 256) accS[i] = 0.f;
  if (tid < 64) lsumS[tid] = 0.f;
  __syncthreads();

  // Q fragments: all 64 q (B-operand: n=q=l15, k=d=ks*32+quad*8+j), in regs
  short8 qf[4][2];
#pragma unroll
  for (int qt = 0; qt < 4; ++qt)
#pragma unroll
    for (int ks = 0; ks < 2; ++ks)
      qf[qt][ks] = *(const short8*)(qkv + qkvB +
          (size_t)(q0 + qt * 16 + l15) * QKV_LD + h * HD + ks * 32 + quad * 8);

  const int sr8 = lane >> 3, sp8 = lane & 7;
  const unsigned short* kP = qkv + qkvB + DIM + h * HD
      + (size_t)(wave * 16 + sr8) * QKV_LD + (sp8 ^ sr8) * 8;
  const unsigned short* vP = vt2 + (size_t)bh * 131072 + wave * 1024 + lane * 8;

  unsigned short* slab0 = &stage[0][wave][0];
  unsigned short* slab1 = &stage[1][wave][0];

  f32x4 oacc[4][4] = {};   // [dt][qt]: O^T[d=dt*16+quad*4+r][q=qt*16+l15]
  float lsum[4] = {};

  auto stage4 = [&](unsigned short* sl) {
    gl_lds16(kP,               sl);
    gl_lds16(kP + 8 * QKV_LD,  sl + 512);
    gl_lds16(vP,               sl + 1024);
    gl_lds16(vP + 512,         sl + 1536);
    kP += (size_t)64 * QKV_LD;
    vP += 4096;
  };

  auto compute = [&](const unsigned short* cur) {
    short8 kf0 = *(const short8*)(cur + l15 * 64 + ((quad       ^ (l15 & 7)) * 8));
    short8 kf1 = *(const short8*)(cur + l15 * 64 + (((4 + quad) ^ (l15 & 7)) * 8));
    f32x4 sacc[4] = {};
#pragma unroll
    for (int qt = 0; qt < 4; ++qt) {
      sacc[qt] = MFMA32(kf0, qf[qt][0], sacc[qt]);
      sacc[qt] = MFMA32(kf1, qf[qt][1], sacc[qt]);
    }
    short4v vf[4];
#pragma unroll
    for (int dt = 0; dt < 4; ++dt)
      vf[dt] = *(const short4v*)(cur + 1024 + (dt * 16 + l15) * 16 + quad * 4);
#pragma unroll
    for (int qt = 0; qt < 4; ++qt) {
      float p0 = EXP2(sacc[qt][0]);
      float p1 = EXP2(sacc[qt][1]);
      float p2 = EXP2(sacc[qt][2]);
      float p3 = EXP2(sacc[qt][3]);
      lsum[qt] += (p0 + p1) + (p2 + p3);
      unsigned r0 = __builtin_bit_cast(unsigned, p0) + 0x8000u;
      unsigned r1 = __builtin_bit_cast(unsigned, p1) + 0x8000u;
      unsigned r2 = __builtin_bit_cast(unsigned, p2) + 0x8000u;
      unsigned r3 = __builtin_bit_cast(unsigned, p3) + 0x8000u;
      uint2 pd;
      pd.x = __builtin_amdgcn_perm(r1, r0, 0x07060302u);
      pd.y = __builtin_amdgcn_perm(r3, r2, 0x07060302u);
      short4v pf = __builtin_bit_cast(short4v, pd);
#pragma unroll
      for (int dt = 0; dt < 4; ++dt)
        oacc[dt][qt] = MFMA16(vf[dt], pf, oacc[dt][qt]);
    }
  };

#define WAIT_VM4()  __asm__ volatile("s_waitcnt vmcnt(4)" ::: "memory")
#define WAIT_VM0()  __asm__ volatile("s_waitcnt vmcnt(0)" ::: "memory")
#define WAIT_LGKM() __asm__ volatile("s_waitcnt lgkmcnt(0)" ::: "memory")

  // pipeline: tiles 0..31; slab re-staged only after lgkmcnt(0) fence
  stage4(slab0);                    // tile 0
  stage4(slab1);                    // tile 1
  for (int t = 0; t < 15; ++t) {
    WAIT_VM4();  compute(slab0);    // tile 2t
    WAIT_LGKM(); stage4(slab0);     // tile 2t+2
    WAIT_VM4();  compute(slab1);    // tile 2t+1
    WAIT_LGKM(); stage4(slab1);     // tile 2t+3
  }
  WAIT_VM4();  compute(slab0);      // tile 30
  WAIT_VM0();  compute(slab1);      // tile 31

  // cross-wave reduction: lsum then O partials
#pragma unroll
  for (int qt = 0; qt < 4; ++qt) {
    float s = lsum[qt];
    s += __shfl_xor(s, 16);
    s += __shfl_xor(s, 32);
    if (quad == 0) atomicAdd(&lsumS[qt * 16 + l15], s);
  }
#pragma unroll
  for (int dt = 0; dt < 4; ++dt)
#pragma unroll
    for (int qt = 0; qt < 4; ++qt) {
      int q = qt * 16 + l15;
      int dbase = dt * 16 + quad * 4;
#pragma unroll
      for (int r = 0; r < 4; ++r)
        atomicAdd(&accS[q * 64 + ((dbase + r + q) & 63)], oacc[dt][qt][r]);
    }
  __syncthreads();

  // store: wave w -> q rows w*16..+15; lane = d (coalesced 128B rows)
  const int d = lane;
  for (int qq = 0; qq < 16; ++qq) {
    int q = wave * 16 + qq;
    float inv = 1.0f / lsumS[q];
    float v = accS[q * 64 + ((d + q) & 63)] * inv;
    aout[(size_t)(b * NSEQ + q0 + q) * DIM + h * HD + d] = f2bf(v);
  }
}

// ---------------------------------------------------------------------------
extern "C" void kernel_launch(void* const* d_in, const int* in_sizes, int n_in,
                              void* d_out, int out_size, void* d_ws, size_t ws_size,
                              hipStream_t stream) {
  (void)in_sizes; (void)n_in; (void)out_size; (void)ws_size;
  const float* x      = (const float*)d_in[0];
  const float* qkv_w  = (const float*)d_in[1];
  const float* qkv_b  = (const float*)d_in[2];
  const float* proj_w = (const float*)d_in[3];
  const float* proj_b = (const float*)d_in[4];
  float* out = (float*)d_out;

  char* ws = (char*)d_ws;
  unsigned short* xb   = (unsigned short*)(ws);                       // 8 MB
  unsigned short* wqb  = (unsigned short*)(ws + ( 8u << 20));         // 6 MB
  unsigned short* wpb  = (unsigned short*)(ws + (14u << 20));         // 2 MB
  unsigned short* qkv  = (unsigned short*)(ws + (16u << 20));         // 24 MB
  unsigned short* vtw  = (unsigned short*)(ws + (40u << 20));         // 8 MB
  unsigned short* attn = (unsigned short*)(ws + (48u << 20));         // 8 MB

  cast_bf16_3<<<8192, 256, 0, stream>>>(x, qkv_w, proj_w, xb, wqb, wpb);
  gemm_nt<<<dim3(32, 24), 256, 0, stream>>>(xb, wqb, qkv_b, DIM, 1, qkv, vtw, nullptr);
  attn_fused<<<1024, 256, 0, stream>>>(qkv, vtw, attn);
  gemm_nt64<<<dim3(64, 8), 256, 0, stream>>>(attn, wpb, proj_b, DIM, out);
}